// Round 1
// 374.627 us; speedup vs baseline: 1.0074x; 1.0074x over previous
//
#include <hip/hip_runtime.h>

typedef unsigned short u16;
typedef u16 u16x8 __attribute__((ext_vector_type(8)));
typedef __bf16 bf16x8 __attribute__((ext_vector_type(8)));
typedef float f32x4 __attribute__((ext_vector_type(4)));

#define NPIX 100352           // 32*56*56
#define KTOT 2304             // 3*3*256
#define IMG_PAD (58 * 58 * 256)

static __device__ __forceinline__ u16 f2bf(float f) {
  unsigned u = __float_as_uint(f);
  return (u16)((u + 0x7fffu + ((u >> 16) & 1u)) >> 16);
}

static __device__ __forceinline__ void gld_lds16(const u16* g, u16* l) {
  __builtin_amdgcn_global_load_lds(
      (const __attribute__((address_space(1))) void*)g,
      (__attribute__((address_space(3))) void*)l, 16, 0, 0);
}

// ---------- scale[f] = sum_k |w[k][f]| ----------
__global__ void scale_accum_k(const float* __restrict__ w, float* __restrict__ scale) {
  const int t = threadIdx.x;
  const float* p = w + (long)blockIdx.x * 64 * 256 + t;
  float acc = 0.f;
#pragma unroll
  for (int e = 0; e < 64; ++e) acc += fabsf(p[(long)e * 256]);
  atomicAdd(&scale[t], acc);
}

// ---------- wp[f][k] = bf16( scale[f]/2304 * sign(w[k][f]) * mask[k][f] ) ----------
__global__ void pack_w_k(const float* __restrict__ w, const float* __restrict__ mask,
                         const float* __restrict__ ssum, u16* __restrict__ wp) {
  __shared__ u16 t[128][33];
  const int k0 = blockIdx.x * 32;
  const int f0 = blockIdx.y * 128;
  const int tid = threadIdx.x;
#pragma unroll
  for (int i = 0; i < 16; ++i) {
    int idx = tid + i * 256;
    int kk = idx >> 7;
    int ff = idx & 127;
    long g = (long)(k0 + kk) * 256 + f0 + ff;
    float wv = w[g];
    float mv = mask[g];
    float sc = ssum[f0 + ff] * (1.0f / 2304.0f);
    float sg = (wv > 0.f) ? 1.f : ((wv < 0.f) ? -1.f : 0.f);
    t[ff][kk] = f2bf(sc * sg * mv);
  }
  __syncthreads();
#pragma unroll
  for (int i = 0; i < 8; ++i) {
    int idx = tid + i * 256;
    int row = idx >> 4;
    int c = idx & 15;
    unsigned v = (unsigned)t[row][2 * c] | ((unsigned)t[row][2 * c + 1] << 16);
    *(unsigned*)(wp + (long)(f0 + row) * KTOT + k0 + 2 * c) = v;
  }
}

// ---------- x fp32 -> bf16 padded [32][58][58][256], zero border written here ----------
__global__ void fill_xpad2_k(const float* __restrict__ x, u16* __restrict__ xp) {
  const long idx = (long)blockIdx.x * 256 + threadIdx.x;   // one u16x8 chunk
  const int c = (int)(idx & 31);
  const long p = idx >> 5;                // img*3364 + ph*58 + pw
  const int img = (int)(p / 3364);
  const int r = (int)(p % 3364);
  const int ph = r / 58, pw = r % 58;
  u16x8 v = {0, 0, 0, 0, 0, 0, 0, 0};
  if (ph >= 1 && ph <= 56 && pw >= 1 && pw <= 56) {
    const float* s = x + ((long)img * 3136 + (ph - 1) * 56 + (pw - 1)) * 256 + c * 8;
    float4 a = *(const float4*)s;
    float4 b = *(const float4*)(s + 4);
    v[0] = f2bf(a.x); v[1] = f2bf(a.y); v[2] = f2bf(a.z); v[3] = f2bf(a.w);
    v[4] = f2bf(b.x); v[5] = f2bf(b.y); v[6] = f2bf(b.z); v[7] = f2bf(b.w);
  }
  *(u16x8*)(xp + idx * 8) = v;
}

// ---------- implicit-GEMM conv: depth-2 counted-vmcnt pipeline (T3/T4-min) ----------
// C[M=100352,N=256] = A[M,K=2304]*B^T; 128x128 tile, 4 waves, 4x4 MFMA 16x16x32 bf16.
// LDS rows: 64 u16 = 128 B = 8 chunks of 16 B; chunk swizzle pc = lc ^ (row&7).
// Double-buffered (64 KB LDS, 2 blocks/CU). Per step: issue next tile's 8 DMA,
// s_waitcnt vmcnt(8) (cur tile landed, next stays in flight), raw barrier, MFMA,
// raw barrier. NO __syncthreads in the loop (it would drain vmcnt(0)).
__global__ __launch_bounds__(256) void conv_gemm5_k(
    const u16* __restrict__ xpad, const u16* __restrict__ wp, float* __restrict__ out) {
  __shared__ u16 As[2][128 * 64];   // 2 x 16 KB
  __shared__ u16 Bs[2][128 * 64];   // 2 x 16 KB

  const int tid = threadIdx.x;
  const int lane = tid & 63;
  const int wv = tid >> 6;

  // 1D grid 1568 = 8 XCD x 196; bijective swizzle so (m,0)/(m,1) pairs and
  // neighboring m-tiles (shared halo) land on the same XCD's L2.
  const int orig = blockIdx.x;
  const int swz = (orig & 7) * 196 + (orig >> 3);
  const int m0 = (swz >> 1) * 128;
  const int n0 = (swz & 1) * 128;

  // --- staging map: DMA instr i (i=0..3), wave wv covers rows [(i*4+wv)*8, +8)
  const int lsub = lane >> 3;                       // 0..7
  const int lc = (lane & 7) ^ (lsub & 7);           // swizzle
  const u16* aptr[4];
  const u16* bptr[4];
#pragma unroll
  for (int i = 0; i < 4; ++i) {
    const int row = (i * 4 + wv) * 8 + lsub;        // 0..127, each exactly once
    const int m = m0 + row;
    const int img = m / 3136, q = m % 3136;
    aptr[i] = xpad + (long)img * IMG_PAD + ((q / 56 + 1) * 58 + (q % 56) + 1) * 256 + lc * 8;
    bptr[i] = wp + (long)(n0 + row) * KTOT + lc * 8;
  }
  const int ldsb = wv * 512;   // wave-uniform LDS base (u16 units)

  // --- MFMA lane mapping
  const int lm = lane & 15, kq = lane >> 4;
  const int wm = wv & 1, wn = wv >> 1;
  int aoff[2], boff[2];
#pragma unroll
  for (int ct = 0; ct < 2; ++ct) {
    const int pc = ((ct * 4 + kq) ^ (lm & 7)) * 8;
    aoff[ct] = (wm * 64 + lm) * 64 + pc;
    boff[ct] = (wn * 64 + lm) * 64 + pc;
  }

  f32x4 acc[4][4] = {};

  // K-step kt = 0..35: khw = kt>>2, ka = d(khw)+(kt&3)*64, kb = kt*64
  // prologue: stage tile 0 into buf 0 (khw=0 -> d = (-58-1)*256)
  {
    const int ka = -59 * 256;
#pragma unroll
    for (int i = 0; i < 4; ++i) {
      gld_lds16(aptr[i] + ka, As[0] + i * 2048 + ldsb);
      gld_lds16(bptr[i], Bs[0] + i * 2048 + ldsb);
    }
  }

  for (int kt = 0; kt < 36; ++kt) {
    const int cur = kt & 1;
    if (kt < 35) {
      const int kn = kt + 1;
      const int khw = kn >> 2;
      const int d = ((khw / 3 - 1) * 58 + (khw % 3 - 1)) * 256;   // halo offset (u16)
      const int ka = d + (kn & 3) * 64;
      const int kb = kn * 64;
#pragma unroll
      for (int i = 0; i < 4; ++i) {
        gld_lds16(aptr[i] + ka, As[cur ^ 1] + i * 2048 + ldsb);
        gld_lds16(bptr[i] + kb, Bs[cur ^ 1] + i * 2048 + ldsb);
      }
      // this wave's 8 tile-kt DMAs done; tile kt+1's 8 stay in flight
      asm volatile("s_waitcnt vmcnt(8)" ::: "memory");
    } else {
      asm volatile("s_waitcnt vmcnt(0)" ::: "memory");
    }
    __builtin_amdgcn_s_barrier();       // all waves' tile-kt DMAs visible
    asm volatile("" ::: "memory");

#pragma unroll
    for (int ct = 0; ct < 2; ++ct) {
      bf16x8 av[4], bv[4];
#pragma unroll
      for (int mi = 0; mi < 4; ++mi) av[mi] = *(const bf16x8*)(As[cur] + aoff[ct] + mi * 1024);
#pragma unroll
      for (int ni = 0; ni < 4; ++ni) bv[ni] = *(const bf16x8*)(Bs[cur] + boff[ct] + ni * 1024);
#pragma unroll
      for (int mi = 0; mi < 4; ++mi)
#pragma unroll
        for (int ni = 0; ni < 4; ++ni)
          acc[mi][ni] = __builtin_amdgcn_mfma_f32_16x16x32_bf16(av[mi], bv[ni], acc[mi][ni], 0, 0, 0);
    }

    asm volatile("" ::: "memory");
    __builtin_amdgcn_s_barrier();       // reads of buf[cur] retired block-wide
    asm volatile("" ::: "memory");
  }

  // D: col = lane&15 (n), row = quad*4 + reg (m)
  float* op = out + (long)(m0 + wm * 64 + kq * 4) * 256 + n0 + wn * 64 + lm;
#pragma unroll
  for (int mi = 0; mi < 4; ++mi) {
#pragma unroll
    for (int ni = 0; ni < 4; ++ni) {
      float* p = op + (long)mi * 16 * 256 + ni * 16;
      f32x4 v = acc[mi][ni];
      p[0] = v[0];
      p[256] = v[1];
      p[512] = v[2];
      p[768] = v[3];
    }
  }
}

// ---------- fallback (round-1 verified path) if ws too small for xpad ----------
__global__ __launch_bounds__(256) void conv_gemm_fb_k(
    const float* __restrict__ x, const u16* __restrict__ wp, float* __restrict__ out) {
  __shared__ u16 As[128 * 40];
  __shared__ u16 Bs[128 * 40];
  const int tid = threadIdx.x;
  const int m0 = blockIdx.x * 128;
  const int n0 = blockIdx.y * 128;
  const int cc = tid & 3;
  const int r0 = tid >> 2;
  const int gm0 = m0 + r0;
  const int gm1 = gm0 + 64;
  const int pix0 = gm0 % 3136, oh0 = pix0 / 56, ow0 = pix0 % 56;
  const int pix1 = gm1 % 3136, oh1 = pix1 / 56, ow1 = pix1 % 56;
  const int lane = tid & 63;
  const int wv = tid >> 6;
  const int wm = wv & 1, wn = wv >> 1;
  const int lm = lane & 15, kq = lane >> 4;
  const int aoff = (wm * 64 + lm) * 40 + kq * 8;
  const int boff = (wn * 64 + lm) * 40 + kq * 8;
  u16* as0 = As + r0 * 40 + cc * 8;
  u16* as1 = As + (r0 + 64) * 40 + cc * 8;
  u16* bs0 = Bs + r0 * 40 + cc * 8;
  u16* bs1 = Bs + (r0 + 64) * 40 + cc * 8;
  const u16* wr0 = wp + (long)(n0 + r0) * KTOT + cc * 8;
  const u16* wr1 = wr0 + (long)64 * KTOT;
  f32x4 acc[4][4] = {};
  for (int khw = 0; khw < 9; ++khw) {
    const int dh = khw / 3 - 1;
    const int dw = khw % 3 - 1;
    const bool v0 = ((unsigned)(oh0 + dh) < 56u) && ((unsigned)(ow0 + dw) < 56u);
    const bool v1 = ((unsigned)(oh1 + dh) < 56u) && ((unsigned)(ow1 + dw) < 56u);
    const long p0 = ((long)gm0 + dh * 56 + dw) * 256 + cc * 8;
    const long p1 = ((long)gm1 + dh * 56 + dw) * 256 + cc * 8;
    const u16* wk0 = wr0 + khw * 256;
    const u16* wk1 = wr1 + khw * 256;
    for (int ct = 0; ct < 8; ++ct) {
      const int ci0 = ct * 32;
      u16x8 a0 = {0,0,0,0,0,0,0,0}, a1 = {0,0,0,0,0,0,0,0};
      float4 l0 = make_float4(0,0,0,0), h0 = make_float4(0,0,0,0);
      float4 l1 = make_float4(0,0,0,0), h1 = make_float4(0,0,0,0);
      if (v0) { l0 = *(const float4*)(x + p0 + ci0); h0 = *(const float4*)(x + p0 + ci0 + 4); }
      if (v1) { l1 = *(const float4*)(x + p1 + ci0); h1 = *(const float4*)(x + p1 + ci0 + 4); }
      a0[0]=f2bf(l0.x); a0[1]=f2bf(l0.y); a0[2]=f2bf(l0.z); a0[3]=f2bf(l0.w);
      a0[4]=f2bf(h0.x); a0[5]=f2bf(h0.y); a0[6]=f2bf(h0.z); a0[7]=f2bf(h0.w);
      a1[0]=f2bf(l1.x); a1[1]=f2bf(l1.y); a1[2]=f2bf(l1.z); a1[3]=f2bf(l1.w);
      a1[4]=f2bf(h1.x); a1[5]=f2bf(h1.y); a1[6]=f2bf(h1.z); a1[7]=f2bf(h1.w);
      u16x8 b0 = *(const u16x8*)(wk0 + ci0);
      u16x8 b1 = *(const u16x8*)(wk1 + ci0);
      __syncthreads();
      *(u16x8*)as0 = a0; *(u16x8*)as1 = a1;
      *(u16x8*)bs0 = b0; *(u16x8*)bs1 = b1;
      __syncthreads();
      bf16x8 av[4], bv[4];
#pragma unroll
      for (int i = 0; i < 4; ++i) av[i] = *(const bf16x8*)(As + aoff + i * 640);
#pragma unroll
      for (int i = 0; i < 4; ++i) bv[i] = *(const bf16x8*)(Bs + boff + i * 640);
#pragma unroll
      for (int mi = 0; mi < 4; ++mi)
#pragma unroll
        for (int ni = 0; ni < 4; ++ni)
          acc[mi][ni] = __builtin_amdgcn_mfma_f32_16x16x32_bf16(av[mi], bv[ni], acc[mi][ni], 0, 0, 0);
    }
  }
  float* op = out + (long)(m0 + wm * 64 + kq * 4) * 256 + n0 + wn * 64 + lm;
#pragma unroll
  for (int mi = 0; mi < 4; ++mi)
#pragma unroll
    for (int ni = 0; ni < 4; ++ni) {
      float* p = op + (long)mi * 16 * 256 + ni * 16;
      f32x4 v = acc[mi][ni];
      p[0] = v[0]; p[256] = v[1]; p[512] = v[2]; p[768] = v[3];
    }
}

extern "C" void kernel_launch(void* const* d_in, const int* in_sizes, int n_in,
                              void* d_out, int out_size, void* d_ws, size_t ws_size,
                              hipStream_t stream) {
  const float* x = (const float*)d_in[0];
  const float* w = (const float*)d_in[1];
  const float* mask = (const float*)d_in[2];
  float* out = (float*)d_out;

  float* scale = (float*)d_ws;                       // 1024 B + pad
  u16* wp = (u16*)((char*)d_ws + 1088);              // 1,179,648 B  [f][k] bf16
  u16* xpad = (u16*)((char*)d_ws + 1088 + 1179648);  // 55,115,776 B padded bf16 x
  const size_t xpad_bytes = (size_t)32 * IMG_PAD * 2;
  const size_t need = 1088 + 1179648 + xpad_bytes;

  hipMemsetAsync(d_ws, 0, 1088, stream);
  scale_accum_k<<<36, 256, 0, stream>>>(w, scale);
  pack_w_k<<<dim3(72, 2), 256, 0, stream>>>(w, mask, scale, wp);
  if (ws_size >= need) {
    fill_xpad2_k<<<(32 * 3364 * 32) / 256, 256, 0, stream>>>(x, xpad);
    conv_gemm5_k<<<1568, 256, 0, stream>>>(xpad, wp, out);
  } else {
    conv_gemm_fb_k<<<dim3(784, 2), 256, 0, stream>>>(x, wp, out);
  }
}

// Round 2
// 345.740 us; speedup vs baseline: 1.0916x; 1.0836x over previous
//
#include <hip/hip_runtime.h>

typedef unsigned short u16;
typedef u16 u16x8 __attribute__((ext_vector_type(8)));
typedef __bf16 bf16x8 __attribute__((ext_vector_type(8)));
typedef float f32x4 __attribute__((ext_vector_type(4)));

#define NPIX 100352           // 32*56*56
#define KTOT 2304             // 3*3*256
#define IMG_PAD (58 * 58 * 256)

static __device__ __forceinline__ u16 f2bf(float f) {
  unsigned u = __float_as_uint(f);
  return (u16)((u + 0x7fffu + ((u >> 16) & 1u)) >> 16);
}

static __device__ __forceinline__ void gld_lds16(const u16* g, u16* l) {
  __builtin_amdgcn_global_load_lds(
      (const __attribute__((address_space(1))) void*)g,
      (__attribute__((address_space(3))) void*)l, 16, 0, 0);
}

// ---------- scale[f] = sum_k |w[k][f]| ----------
__global__ void scale_accum_k(const float* __restrict__ w, float* __restrict__ scale) {
  const int t = threadIdx.x;
  const float* p = w + (long)blockIdx.x * 64 * 256 + t;
  float acc = 0.f;
#pragma unroll
  for (int e = 0; e < 64; ++e) acc += fabsf(p[(long)e * 256]);
  atomicAdd(&scale[t], acc);
}

// ---------- wp[f][k] = bf16( scale[f]/2304 * sign(w[k][f]) * mask[k][f] ) ----------
__global__ void pack_w_k(const float* __restrict__ w, const float* __restrict__ mask,
                         const float* __restrict__ ssum, u16* __restrict__ wp) {
  __shared__ u16 t[128][33];
  const int k0 = blockIdx.x * 32;
  const int f0 = blockIdx.y * 128;
  const int tid = threadIdx.x;
#pragma unroll
  for (int i = 0; i < 16; ++i) {
    int idx = tid + i * 256;
    int kk = idx >> 7;
    int ff = idx & 127;
    long g = (long)(k0 + kk) * 256 + f0 + ff;
    float wv = w[g];
    float mv = mask[g];
    float sc = ssum[f0 + ff] * (1.0f / 2304.0f);
    float sg = (wv > 0.f) ? 1.f : ((wv < 0.f) ? -1.f : 0.f);
    t[ff][kk] = f2bf(sc * sg * mv);
  }
  __syncthreads();
#pragma unroll
  for (int i = 0; i < 8; ++i) {
    int idx = tid + i * 256;
    int row = idx >> 4;
    int c = idx & 15;
    unsigned v = (unsigned)t[row][2 * c] | ((unsigned)t[row][2 * c + 1] << 16);
    *(unsigned*)(wp + (long)(f0 + row) * KTOT + k0 + 2 * c) = v;
  }
}

// ---------- x fp32 -> bf16 padded [32][58][58][256] — division-free 2D grid ----------
// grid (58, 32): block = (img=blockIdx.y, ph=blockIdx.x); 1856 u16x8 chunks per row,
// 256 threads, ~7.25 chunks/thread. All index math is 32-bit shift/mask.
__global__ __launch_bounds__(256) void fill_xpad3_k(const float* __restrict__ x,
                                                    u16* __restrict__ xp) {
  const int img = blockIdx.y;
  const int ph = blockIdx.x;                       // 0..57
  u16* rowp = xp + ((img * 58 + ph) * 58) * 256;
  const bool irow = (ph >= 1 && ph <= 56);
  const float* xrow = x + ((long)img * 3136 + (ph - 1) * 56) * 256;
  for (int i = threadIdx.x; i < 58 * 32; i += 256) {
    const int pw = i >> 5;                         // 0..57
    const int c8 = (i & 31) * 8;                   // channel chunk base
    u16x8 v = {0, 0, 0, 0, 0, 0, 0, 0};
    if (irow && pw >= 1 && pw <= 56) {
      const float* s = xrow + (pw - 1) * 256 + c8;
      float4 a = *(const float4*)s;
      float4 b = *(const float4*)(s + 4);
      v[0] = f2bf(a.x); v[1] = f2bf(a.y); v[2] = f2bf(a.z); v[3] = f2bf(a.w);
      v[4] = f2bf(b.x); v[5] = f2bf(b.y); v[6] = f2bf(b.z); v[7] = f2bf(b.w);
    }
    *(u16x8*)(rowp + pw * 256 + c8) = v;
  }
}

// ---------- implicit-GEMM conv: depth-2 counted-vmcnt pipeline, fully unrolled ----------
// C[M=100352,N=256] = A[M,K=2304]*B^T; 128x128 tile, 4 waves, 4x4 MFMA 16x16x32 bf16.
// LDS rows: 64 u16 = 128 B = 8 chunks of 16 B; chunk swizzle pc = lc ^ (row&7).
// Double-buffered (64 KB LDS). Per step: issue next tile's 8 DMA, s_waitcnt vmcnt(8)
// (cur tile landed, next stays in flight), raw barrier, MFMA, raw barrier.
// kt-loop fully unrolled: khw/3, khw%3, cur, ka/kb all fold to constants.
__global__ __launch_bounds__(256) void conv_gemm5_k(
    const u16* __restrict__ xpad, const u16* __restrict__ wp, float* __restrict__ out) {
  __shared__ u16 As[2][128 * 64];   // 2 x 16 KB
  __shared__ u16 Bs[2][128 * 64];   // 2 x 16 KB

  const int tid = threadIdx.x;
  const int lane = tid & 63;
  const int wv = tid >> 6;

  // 1D grid 1568 = 8 XCD x 196; bijective swizzle for XCD-L2 locality.
  const int orig = blockIdx.x;
  const int swz = (orig & 7) * 196 + (orig >> 3);
  const int m0 = (swz >> 1) * 128;
  const int n0 = (swz & 1) * 128;

  // --- staging map: DMA instr i (i=0..3), wave wv covers rows [(i*4+wv)*8, +8)
  const int lsub = lane >> 3;                       // 0..7
  const int lc = (lane & 7) ^ (lsub & 7);           // swizzle
  const u16* aptr[4];
  const u16* bptr[4];
#pragma unroll
  for (int i = 0; i < 4; ++i) {
    const int row = (i * 4 + wv) * 8 + lsub;        // 0..127, each exactly once
    const int m = m0 + row;
    const int img = m / 3136, q = m % 3136;
    aptr[i] = xpad + (long)img * IMG_PAD + ((q / 56 + 1) * 58 + (q % 56) + 1) * 256 + lc * 8;
    bptr[i] = wp + (long)(n0 + row) * KTOT + lc * 8;
  }
  const int ldsb = wv * 512;   // wave-uniform LDS base (u16 units)

  // --- MFMA lane mapping
  const int lm = lane & 15, kq = lane >> 4;
  const int wm = wv & 1, wn = wv >> 1;
  int aoff[2], boff[2];
#pragma unroll
  for (int ct = 0; ct < 2; ++ct) {
    const int pc = ((ct * 4 + kq) ^ (lm & 7)) * 8;
    aoff[ct] = (wm * 64 + lm) * 64 + pc;
    boff[ct] = (wn * 64 + lm) * 64 + pc;
  }

  f32x4 acc[4][4] = {};

  // prologue: stage tile 0 into buf 0 (khw=0 -> d = (-58-1)*256)
  {
    const int ka = -59 * 256;
#pragma unroll
    for (int i = 0; i < 4; ++i) {
      gld_lds16(aptr[i] + ka, As[0] + i * 2048 + ldsb);
      gld_lds16(bptr[i], Bs[0] + i * 2048 + ldsb);
    }
  }

#pragma unroll
  for (int kt = 0; kt < 36; ++kt) {
    const int cur = kt & 1;
    if (kt < 35) {
      const int kn = kt + 1;
      const int khw = kn >> 2;
      const int d = ((khw / 3 - 1) * 58 + (khw % 3 - 1)) * 256;   // constant under unroll
      const int ka = d + (kn & 3) * 64;
      const int kb = kn * 64;
#pragma unroll
      for (int i = 0; i < 4; ++i) {
        gld_lds16(aptr[i] + ka, As[cur ^ 1] + i * 2048 + ldsb);
        gld_lds16(bptr[i] + kb, Bs[cur ^ 1] + i * 2048 + ldsb);
      }
      // this wave's 8 tile-kt DMAs done; tile kt+1's 8 stay in flight
      asm volatile("s_waitcnt vmcnt(8)" ::: "memory");
    } else {
      asm volatile("s_waitcnt vmcnt(0)" ::: "memory");
    }
    __builtin_amdgcn_s_barrier();       // all waves' tile-kt DMAs visible
    asm volatile("" ::: "memory");

#pragma unroll
    for (int ct = 0; ct < 2; ++ct) {
      bf16x8 av[4], bv[4];
#pragma unroll
      for (int mi = 0; mi < 4; ++mi) av[mi] = *(const bf16x8*)(As[cur] + aoff[ct] + mi * 1024);
#pragma unroll
      for (int ni = 0; ni < 4; ++ni) bv[ni] = *(const bf16x8*)(Bs[cur] + boff[ct] + ni * 1024);
#pragma unroll
      for (int mi = 0; mi < 4; ++mi)
#pragma unroll
        for (int ni = 0; ni < 4; ++ni)
          acc[mi][ni] = __builtin_amdgcn_mfma_f32_16x16x32_bf16(av[mi], bv[ni], acc[mi][ni], 0, 0, 0);
    }

    asm volatile("" ::: "memory");
    __builtin_amdgcn_s_barrier();       // reads of buf[cur] retired block-wide
    asm volatile("" ::: "memory");
  }

  // D: col = lane&15 (n), row = quad*4 + reg (m)
  float* op = out + (long)(m0 + wm * 64 + kq * 4) * 256 + n0 + wn * 64 + lm;
#pragma unroll
  for (int mi = 0; mi < 4; ++mi) {
#pragma unroll
    for (int ni = 0; ni < 4; ++ni) {
      float* p = op + (long)mi * 16 * 256 + ni * 16;
      f32x4 v = acc[mi][ni];
      p[0] = v[0];
      p[256] = v[1];
      p[512] = v[2];
      p[768] = v[3];
    }
  }
}

// ---------- fallback (round-1 verified path) if ws too small for xpad ----------
__global__ __launch_bounds__(256) void conv_gemm_fb_k(
    const float* __restrict__ x, const u16* __restrict__ wp, float* __restrict__ out) {
  __shared__ u16 As[128 * 40];
  __shared__ u16 Bs[128 * 40];
  const int tid = threadIdx.x;
  const int m0 = blockIdx.x * 128;
  const int n0 = blockIdx.y * 128;
  const int cc = tid & 3;
  const int r0 = tid >> 2;
  const int gm0 = m0 + r0;
  const int gm1 = gm0 + 64;
  const int pix0 = gm0 % 3136, oh0 = pix0 / 56, ow0 = pix0 % 56;
  const int pix1 = gm1 % 3136, oh1 = pix1 / 56, ow1 = pix1 % 56;
  const int lane = tid & 63;
  const int wv = tid >> 6;
  const int wm = wv & 1, wn = wv >> 1;
  const int lm = lane & 15, kq = lane >> 4;
  const int aoff = (wm * 64 + lm) * 40 + kq * 8;
  const int boff = (wn * 64 + lm) * 40 + kq * 8;
  u16* as0 = As + r0 * 40 + cc * 8;
  u16* as1 = As + (r0 + 64) * 40 + cc * 8;
  u16* bs0 = Bs + r0 * 40 + cc * 8;
  u16* bs1 = Bs + (r0 + 64) * 40 + cc * 8;
  const u16* wr0 = wp + (long)(n0 + r0) * KTOT + cc * 8;
  const u16* wr1 = wr0 + (long)64 * KTOT;
  f32x4 acc[4][4] = {};
  for (int khw = 0; khw < 9; ++khw) {
    const int dh = khw / 3 - 1;
    const int dw = khw % 3 - 1;
    const bool v0 = ((unsigned)(oh0 + dh) < 56u) && ((unsigned)(ow0 + dw) < 56u);
    const bool v1 = ((unsigned)(oh1 + dh) < 56u) && ((unsigned)(ow1 + dw) < 56u);
    const long p0 = ((long)gm0 + dh * 56 + dw) * 256 + cc * 8;
    const long p1 = ((long)gm1 + dh * 56 + dw) * 256 + cc * 8;
    const u16* wk0 = wr0 + khw * 256;
    const u16* wk1 = wr1 + khw * 256;
    for (int ct = 0; ct < 8; ++ct) {
      const int ci0 = ct * 32;
      u16x8 a0 = {0,0,0,0,0,0,0,0}, a1 = {0,0,0,0,0,0,0,0};
      float4 l0 = make_float4(0,0,0,0), h0 = make_float4(0,0,0,0);
      float4 l1 = make_float4(0,0,0,0), h1 = make_float4(0,0,0,0);
      if (v0) { l0 = *(const float4*)(x + p0 + ci0); h0 = *(const float4*)(x + p0 + ci0 + 4); }
      if (v1) { l1 = *(const float4*)(x + p1 + ci0); h1 = *(const float4*)(x + p1 + ci0 + 4); }
      a0[0]=f2bf(l0.x); a0[1]=f2bf(l0.y); a0[2]=f2bf(l0.z); a0[3]=f2bf(l0.w);
      a0[4]=f2bf(h0.x); a0[5]=f2bf(h0.y); a0[6]=f2bf(h0.z); a0[7]=f2bf(h0.w);
      a1[0]=f2bf(l1.x); a1[1]=f2bf(l1.y); a1[2]=f2bf(l1.z); a1[3]=f2bf(l1.w);
      a1[4]=f2bf(h1.x); a1[5]=f2bf(h1.y); a1[6]=f2bf(h1.z); a1[7]=f2bf(h1.w);
      u16x8 b0 = *(const u16x8*)(wk0 + ci0);
      u16x8 b1 = *(const u16x8*)(wk1 + ci0);
      __syncthreads();
      *(u16x8*)as0 = a0; *(u16x8*)as1 = a1;
      *(u16x8*)bs0 = b0; *(u16x8*)bs1 = b1;
      __syncthreads();
      bf16x8 av[4], bv[4];
#pragma unroll
      for (int i = 0; i < 4; ++i) av[i] = *(const bf16x8*)(As + aoff + i * 640);
#pragma unroll
      for (int i = 0; i < 4; ++i) bv[i] = *(const bf16x8*)(Bs + boff + i * 640);
#pragma unroll
      for (int mi = 0; mi < 4; ++mi)
#pragma unroll
        for (int ni = 0; ni < 4; ++ni)
          acc[mi][ni] = __builtin_amdgcn_mfma_f32_16x16x32_bf16(av[mi], bv[ni], acc[mi][ni], 0, 0, 0);
    }
  }
  float* op = out + (long)(m0 + wm * 64 + kq * 4) * 256 + n0 + wn * 64 + lm;
#pragma unroll
  for (int mi = 0; mi < 4; ++mi)
#pragma unroll
    for (int ni = 0; ni < 4; ++ni) {
      float* p = op + (long)mi * 16 * 256 + ni * 16;
      f32x4 v = acc[mi][ni];
      p[0] = v[0]; p[256] = v[1]; p[512] = v[2]; p[768] = v[3];
    }
}

extern "C" void kernel_launch(void* const* d_in, const int* in_sizes, int n_in,
                              void* d_out, int out_size, void* d_ws, size_t ws_size,
                              hipStream_t stream) {
  const float* x = (const float*)d_in[0];
  const float* w = (const float*)d_in[1];
  const float* mask = (const float*)d_in[2];
  float* out = (float*)d_out;

  float* scale = (float*)d_ws;                       // 1024 B + pad
  u16* wp = (u16*)((char*)d_ws + 1088);              // 1,179,648 B  [f][k] bf16
  u16* xpad = (u16*)((char*)d_ws + 1088 + 1179648);  // 55,115,776 B padded bf16 x
  const size_t xpad_bytes = (size_t)32 * IMG_PAD * 2;
  const size_t need = 1088 + 1179648 + xpad_bytes;

  hipMemsetAsync(d_ws, 0, 1088, stream);
  scale_accum_k<<<36, 256, 0, stream>>>(w, scale);
  pack_w_k<<<dim3(72, 2), 256, 0, stream>>>(w, mask, scale, wp);
  if (ws_size >= need) {
    fill_xpad3_k<<<dim3(58, 32), 256, 0, stream>>>(x, xpad);
    conv_gemm5_k<<<1568, 256, 0, stream>>>(xpad, wp, out);
  } else {
    conv_gemm_fb_k<<<dim3(784, 2), 256, 0, stream>>>(x, wp, out);
  }
}

// Round 4
// 334.977 us; speedup vs baseline: 1.1267x; 1.0321x over previous
//
#include <hip/hip_runtime.h>

typedef unsigned short u16;
typedef u16 u16x8 __attribute__((ext_vector_type(8)));
typedef __bf16 bf16x8 __attribute__((ext_vector_type(8)));
typedef float f32x4 __attribute__((ext_vector_type(4)));

#define NPIX 100352           // 32*56*56
#define KTOT 2304             // 3*3*256
#define IMG_PAD (58 * 58 * 256)

static __device__ __forceinline__ u16 f2bf(float f) {
  unsigned u = __float_as_uint(f);
  return (u16)((u + 0x7fffu + ((u >> 16) & 1u)) >> 16);
}

static __device__ __forceinline__ void gld_lds16(const u16* g, u16* l) {
  __builtin_amdgcn_global_load_lds(
      (const __attribute__((address_space(1))) void*)g,
      (__attribute__((address_space(3))) void*)l, 16, 0, 0);
}

// A-panel k-offset (u16) for K-tile kt: halo offset of khw + 64*(kt&3)
static __device__ __forceinline__ int ka_of(int kt) {
  const int khw = kt >> 2;                 // 0..8
  const int q = (khw * 11) >> 5;           // khw/3 for 0..8
  const int r = khw - q * 3;               // khw%3
  return (q * 58 + r - 59) * 256 + (kt & 3) * 64;
}

// ---------- scale[f] = sum_k |w[k][f]| ----------
__global__ void scale_accum_k(const float* __restrict__ w, float* __restrict__ scale) {
  const int t = threadIdx.x;
  const float* p = w + (long)blockIdx.x * 64 * 256 + t;
  float acc = 0.f;
#pragma unroll
  for (int e = 0; e < 64; ++e) acc += fabsf(p[(long)e * 256]);
  atomicAdd(&scale[t], acc);
}

// ---------- wp[f][k] = bf16( scale[f]/2304 * sign(w[k][f]) * mask[k][f] ) ----------
__global__ void pack_w_k(const float* __restrict__ w, const float* __restrict__ mask,
                         const float* __restrict__ ssum, u16* __restrict__ wp) {
  __shared__ u16 t[128][33];
  const int k0 = blockIdx.x * 32;
  const int f0 = blockIdx.y * 128;
  const int tid = threadIdx.x;
#pragma unroll
  for (int i = 0; i < 16; ++i) {
    int idx = tid + i * 256;
    int kk = idx >> 7;
    int ff = idx & 127;
    long g = (long)(k0 + kk) * 256 + f0 + ff;
    float wv = w[g];
    float mv = mask[g];
    float sc = ssum[f0 + ff] * (1.0f / 2304.0f);
    float sg = (wv > 0.f) ? 1.f : ((wv < 0.f) ? -1.f : 0.f);
    t[ff][kk] = f2bf(sc * sg * mv);
  }
  __syncthreads();
#pragma unroll
  for (int i = 0; i < 8; ++i) {
    int idx = tid + i * 256;
    int row = idx >> 4;
    int c = idx & 15;
    unsigned v = (unsigned)t[row][2 * c] | ((unsigned)t[row][2 * c + 1] << 16);
    *(unsigned*)(wp + (long)(f0 + row) * KTOT + k0 + 2 * c) = v;
  }
}

// ---------- x fp32 -> bf16 padded [32][58][58][256] — division-free 2D grid ----------
__global__ __launch_bounds__(256) void fill_xpad3_k(const float* __restrict__ x,
                                                    u16* __restrict__ xp) {
  const int img = blockIdx.y;
  const int ph = blockIdx.x;                       // 0..57
  u16* rowp = xp + ((img * 58 + ph) * 58) * 256;
  const bool irow = (ph >= 1 && ph <= 56);
  const float* xrow = x + ((long)img * 3136 + (ph - 1) * 56) * 256;
  for (int i = threadIdx.x; i < 58 * 32; i += 256) {
    const int pw = i >> 5;                         // 0..57
    const int c8 = (i & 31) * 8;                   // channel chunk base
    u16x8 v = {0, 0, 0, 0, 0, 0, 0, 0};
    if (irow && pw >= 1 && pw <= 56) {
      const float* s = xrow + (pw - 1) * 256 + c8;
      float4 a = *(const float4*)s;
      float4 b = *(const float4*)(s + 4);
      v[0] = f2bf(a.x); v[1] = f2bf(a.y); v[2] = f2bf(a.z); v[3] = f2bf(a.w);
      v[4] = f2bf(b.x); v[5] = f2bf(b.y); v[6] = f2bf(b.z); v[7] = f2bf(b.w);
    }
    *(u16x8*)(rowp + pw * 256 + c8) = v;
  }
}

// ---------- 256x256 8-phase implicit-GEMM conv (T3+T4+T5, m201 template) ----------
// C[M=100352,N=256] = A[M,K=2304]*B^T. 512 thr = 8 waves (2M x 4N), per-wave C 128x64.
// BK=64, dbuf: As/Bs[2][256*64] = 128 KB LDS. Per phase: 4 A ds_read_b128 (+8 B at
// quadrant 0), stage ONE half-tile (2 gld_lds/wave), counted vmcnt(4) at p3/p7 only,
// raw barrier, setprio(1), 16 MFMA, setprio(0), raw barrier.
// Stage plan (iteration J computes kt 2J,2J+1): p0/p1: A(2J+1)->buf1, p2/p3: B(2J+2)
// ->buf0, p4/p5: A(2J+2)->buf0, p6/p7: B(2J+3)->buf1. vmcnt ledger: 12 outstanding
// at each counted wait; vmcnt(4) completes exactly the next K-tile's 8 loads.
#define STAGE_A8(kt, h, b) do { const int _ka = ka_of(kt); \
    gld_lds16(aptr[(h)*2]     + _ka, As[b] + ldso[(h)*2]); \
    gld_lds16(aptr[(h)*2 + 1] + _ka, As[b] + ldso[(h)*2 + 1]); } while (0)
#define STAGE_B8(kt, h, b) do { const int _kb = (kt) * 64; \
    gld_lds16(bptr[(h)*2]     + _kb, Bs[b] + ldso[(h)*2]); \
    gld_lds16(bptr[(h)*2 + 1] + _kb, Bs[b] + ldso[(h)*2 + 1]); } while (0)

__global__ __launch_bounds__(512, 2) void conv_gemm8_k(
    const u16* __restrict__ xpad, const u16* __restrict__ wp, float* __restrict__ out) {
  __shared__ u16 As[2][256 * 64];   // 2 x 32 KB
  __shared__ u16 Bs[2][256 * 64];   // 2 x 32 KB

  const int tid = threadIdx.x;
  const int lane = tid & 63;
  const int wid = tid >> 6;         // 0..7

  // grid 392 = 8 XCD x 49, bijective swizzle (n0 == 0 always; B shared by all blocks)
  const int orig = blockIdx.x;
  const int swz = (orig & 7) * 49 + (orig >> 3);
  const int m0 = swz * 256;

  // --- staging map: octet o = (q>>1)*16 + (q&1)*8 + wid covers rows [o*8, o*8+8)
  const int lsub = lane >> 3;                       // 0..7 row-in-octet
  const int lc = (lane & 7) ^ lsub;                 // logical chunk (XOR swizzle)
  const u16* aptr[4];
  const u16* bptr[4];
  int ldso[4];
#pragma unroll
  for (int q = 0; q < 4; ++q) {
    const int o = (q >> 1) * 16 + (q & 1) * 8 + wid;   // 0..31
    const int row = o * 8 + lsub;                      // 0..255
    const int m = m0 + row;
    const int img = m / 3136, pix = m % 3136;
    aptr[q] = xpad + (long)img * IMG_PAD + ((pix / 56 + 1) * 58 + (pix % 56) + 1) * 256 + lc * 8;
    bptr[q] = wp + (long)row * KTOT + lc * 8;
    ldso[q] = o * 512;                                 // u16 units; DMA adds lane*16B
  }

  // --- MFMA lane mapping (verified layout carried from 128x128 kernel)
  const int lm = lane & 15, kq = lane >> 4;
  const int wm = wid >> 2, wn = wid & 3;
  int pcq[2];
  pcq[0] = (kq ^ (lm & 7)) * 8;
  pcq[1] = ((4 + kq) ^ (lm & 7)) * 8;
  const int aB = (wm * 128 + lm) * 64;   // + pp*2048 + f*1024 + pcq[ct]
  const int bB = (wn * 64 + lm) * 64;    // + ni*1024 + pcq[ct]

  f32x4 acc[8][4] = {};
  bf16x8 bv[4][2];

  // --- prologue: B(0),A(0) -> buf0; B(1) -> buf1; leave B(1)'s 4 loads in flight
  STAGE_B8(0, 0, 0); STAGE_B8(0, 1, 0);
  STAGE_A8(0, 0, 0); STAGE_A8(0, 1, 0);
  STAGE_B8(1, 0, 1); STAGE_B8(1, 1, 1);
  asm volatile("s_waitcnt vmcnt(4)" ::: "memory");
  __builtin_amdgcn_s_barrier();
  asm volatile("" ::: "memory");

  for (int J = 0; J < 17; ++J) {
#pragma unroll
    for (int p = 0; p < 8; ++p) {
      const int buf = p >> 2;           // kt = 2J+buf
      const int pp = p & 3;             // m-quadrant
      if (pp == 0) {
#pragma unroll
        for (int ni = 0; ni < 4; ++ni)
#pragma unroll
          for (int ct = 0; ct < 2; ++ct)
            bv[ni][ct] = *(const bf16x8*)(Bs[buf] + bB + pcq[ct] + ni * 1024);
      }
      bf16x8 av[2][2];
#pragma unroll
      for (int f = 0; f < 2; ++f)
#pragma unroll
        for (int ct = 0; ct < 2; ++ct)
          av[f][ct] = *(const bf16x8*)(As[buf] + aB + pcq[ct] + pp * 2048 + f * 1024);

      if (p == 0)      STAGE_A8(2 * J + 1, 0, 1);
      else if (p == 1) STAGE_A8(2 * J + 1, 1, 1);
      else if (p == 2) STAGE_B8(2 * J + 2, 0, 0);
      else if (p == 3) { STAGE_B8(2 * J + 2, 1, 0);
                         asm volatile("s_waitcnt vmcnt(4)" ::: "memory"); }
      else if (p == 4) STAGE_A8(2 * J + 2, 0, 0);
      else if (p == 5) STAGE_A8(2 * J + 2, 1, 0);
      else if (p == 6) STAGE_B8(2 * J + 3, 0, 1);
      else             { STAGE_B8(2 * J + 3, 1, 1);
                         asm volatile("s_waitcnt vmcnt(4)" ::: "memory"); }

      __builtin_amdgcn_s_barrier();
      asm volatile("" ::: "memory");
      __builtin_amdgcn_s_setprio(1);
#pragma unroll
      for (int ct = 0; ct < 2; ++ct)
#pragma unroll
        for (int f = 0; f < 2; ++f)
#pragma unroll
          for (int ni = 0; ni < 4; ++ni)
            acc[pp * 2 + f][ni] = __builtin_amdgcn_mfma_f32_16x16x32_bf16(
                av[f][ct], bv[ni][ct], acc[pp * 2 + f][ni], 0, 0, 0);
      __builtin_amdgcn_s_setprio(0);
      asm volatile("" ::: "memory");
      __builtin_amdgcn_s_barrier();
      asm volatile("" ::: "memory");
    }
  }

  // --- peeled last iteration J=17 (kt 34,35): only A(35) still needs staging
#pragma unroll
  for (int p = 0; p < 8; ++p) {
    const int buf = p >> 2;
    const int pp = p & 3;
    if (pp == 0) {
#pragma unroll
      for (int ni = 0; ni < 4; ++ni)
#pragma unroll
        for (int ct = 0; ct < 2; ++ct)
          bv[ni][ct] = *(const bf16x8*)(Bs[buf] + bB + pcq[ct] + ni * 1024);
    }
    bf16x8 av[2][2];
#pragma unroll
    for (int f = 0; f < 2; ++f)
#pragma unroll
      for (int ct = 0; ct < 2; ++ct)
        av[f][ct] = *(const bf16x8*)(As[buf] + aB + pcq[ct] + pp * 2048 + f * 1024);

    if (p == 0)      STAGE_A8(35, 0, 1);
    else if (p == 1) STAGE_A8(35, 1, 1);
    else if (p == 3) asm volatile("s_waitcnt vmcnt(0)" ::: "memory");

    __builtin_amdgcn_s_barrier();
    asm volatile("" ::: "memory");
    __builtin_amdgcn_s_setprio(1);
#pragma unroll
    for (int ct = 0; ct < 2; ++ct)
#pragma unroll
      for (int f = 0; f < 2; ++f)
#pragma unroll
        for (int ni = 0; ni < 4; ++ni)
          acc[pp * 2 + f][ni] = __builtin_amdgcn_mfma_f32_16x16x32_bf16(
              av[f][ct], bv[ni][ct], acc[pp * 2 + f][ni], 0, 0, 0);
    __builtin_amdgcn_s_setprio(0);
    asm volatile("" ::: "memory");
    __builtin_amdgcn_s_barrier();
    asm volatile("" ::: "memory");
  }

  // --- C-write: col = lane&15 (n), row = kq*4 + reg (m)
  float* op = out + (long)(m0 + wm * 128 + kq * 4) * 256 + wn * 64 + lm;
#pragma unroll
  for (int mi = 0; mi < 8; ++mi) {
#pragma unroll
    for (int ni = 0; ni < 4; ++ni) {
      float* p = op + (long)mi * 16 * 256 + ni * 16;
      f32x4 v = acc[mi][ni];
      p[0] = v[0];
      p[256] = v[1];
      p[512] = v[2];
      p[768] = v[3];
    }
  }
}

// ---------- fallback (round-1 verified path) if ws too small for xpad ----------
__global__ __launch_bounds__(256) void conv_gemm_fb_k(
    const float* __restrict__ x, const u16* __restrict__ wp, float* __restrict__ out) {
  __shared__ u16 As[128 * 40];
  __shared__ u16 Bs[128 * 40];
  const int tid = threadIdx.x;
  const int m0 = blockIdx.x * 128;
  const int n0 = blockIdx.y * 128;
  const int cc = tid & 3;
  const int r0 = tid >> 2;
  const int gm0 = m0 + r0;
  const int gm1 = gm0 + 64;
  const int pix0 = gm0 % 3136, oh0 = pix0 / 56, ow0 = pix0 % 56;
  const int pix1 = gm1 % 3136, oh1 = pix1 / 56, ow1 = pix1 % 56;
  const int lane = tid & 63;
  const int wv = tid >> 6;
  const int wm = wv & 1, wn = wv >> 1;
  const int lm = lane & 15, kq = lane >> 4;
  const int aoff = (wm * 64 + lm) * 40 + kq * 8;
  const int boff = (wn * 64 + lm) * 40 + kq * 8;
  u16* as0 = As + r0 * 40 + cc * 8;
  u16* as1 = As + (r0 + 64) * 40 + cc * 8;
  u16* bs0 = Bs + r0 * 40 + cc * 8;
  u16* bs1 = Bs + (r0 + 64) * 40 + cc * 8;
  const u16* wr0 = wp + (long)(n0 + r0) * KTOT + cc * 8;
  const u16* wr1 = wr0 + (long)64 * KTOT;
  f32x4 acc[4][4] = {};
  for (int khw = 0; khw < 9; ++khw) {
    const int dh = khw / 3 - 1;
    const int dw = khw % 3 - 1;
    const bool v0 = ((unsigned)(oh0 + dh) < 56u) && ((unsigned)(ow0 + dw) < 56u);
    const bool v1 = ((unsigned)(oh1 + dh) < 56u) && ((unsigned)(ow1 + dw) < 56u);
    const long p0 = ((long)gm0 + dh * 56 + dw) * 256 + cc * 8;
    const long p1 = ((long)gm1 + dh * 56 + dw) * 256 + cc * 8;
    const u16* wk0 = wr0 + khw * 256;
    const u16* wk1 = wr1 + khw * 256;
    for (int ct = 0; ct < 8; ++ct) {
      const int ci0 = ct * 32;
      u16x8 a0 = {0,0,0,0,0,0,0,0}, a1 = {0,0,0,0,0,0,0,0};
      float4 l0 = make_float4(0,0,0,0), h0 = make_float4(0,0,0,0);
      float4 l1 = make_float4(0,0,0,0), h1 = make_float4(0,0,0,0);
      if (v0) { l0 = *(const float4*)(x + p0 + ci0); h0 = *(const float4*)(x + p0 + ci0 + 4); }
      if (v1) { l1 = *(const float4*)(x + p1 + ci0); h1 = *(const float4*)(x + p1 + ci0 + 4); }
      a0[0]=f2bf(l0.x); a0[1]=f2bf(l0.y); a0[2]=f2bf(l0.z); a0[3]=f2bf(l0.w);
      a0[4]=f2bf(h0.x); a0[5]=f2bf(h0.y); a0[6]=f2bf(h0.z); a0[7]=f2bf(h0.w);
      a1[0]=f2bf(l1.x); a1[1]=f2bf(l1.y); a1[2]=f2bf(l1.z); a1[3]=f2bf(l1.w);
      a1[4]=f2bf(h1.x); a1[5]=f2bf(h1.y); a1[6]=f2bf(h1.z); a1[7]=f2bf(h1.w);
      u16x8 b0 = *(const u16x8*)(wk0 + ci0);
      u16x8 b1 = *(const u16x8*)(wk1 + ci0);
      __syncthreads();
      *(u16x8*)as0 = a0; *(u16x8*)as1 = a1;
      *(u16x8*)bs0 = b0; *(u16x8*)bs1 = b1;
      __syncthreads();
      bf16x8 av[4], bvv[4];
#pragma unroll
      for (int i = 0; i < 4; ++i) av[i] = *(const bf16x8*)(As + aoff + i * 640);
#pragma unroll
      for (int i = 0; i < 4; ++i) bvv[i] = *(const bf16x8*)(Bs + boff + i * 640);
#pragma unroll
      for (int mi = 0; mi < 4; ++mi)
#pragma unroll
        for (int ni = 0; ni < 4; ++ni)
          acc[mi][ni] = __builtin_amdgcn_mfma_f32_16x16x32_bf16(av[mi], bvv[ni], acc[mi][ni], 0, 0, 0);
    }
  }
  float* op = out + (long)(m0 + wm * 64 + kq * 4) * 256 + n0 + wn * 64 + lm;
#pragma unroll
  for (int mi = 0; mi < 4; ++mi)
#pragma unroll
    for (int ni = 0; ni < 4; ++ni) {
      float* p = op + (long)mi * 16 * 256 + ni * 16;
      f32x4 v = acc[mi][ni];
      p[0] = v[0]; p[256] = v[1]; p[512] = v[2]; p[768] = v[3];
    }
}

extern "C" void kernel_launch(void* const* d_in, const int* in_sizes, int n_in,
                              void* d_out, int out_size, void* d_ws, size_t ws_size,
                              hipStream_t stream) {
  const float* x = (const float*)d_in[0];
  const float* w = (const float*)d_in[1];
  const float* mask = (const float*)d_in[2];
  float* out = (float*)d_out;

  float* scale = (float*)d_ws;                       // 1024 B + pad
  u16* wp = (u16*)((char*)d_ws + 1088);              // 1,179,648 B  [f][k] bf16
  u16* xpad = (u16*)((char*)d_ws + 1088 + 1179648);  // 55,115,776 B padded bf16 x
  const size_t xpad_bytes = (size_t)32 * IMG_PAD * 2;
  const size_t need = 1088 + 1179648 + xpad_bytes;

  hipMemsetAsync(d_ws, 0, 1088, stream);
  scale_accum_k<<<36, 256, 0, stream>>>(w, scale);
  pack_w_k<<<dim3(72, 2), 256, 0, stream>>>(w, mask, scale, wp);
  if (ws_size >= need) {
    fill_xpad3_k<<<dim3(58, 32), 256, 0, stream>>>(x, xpad);
    conv_gemm8_k<<<392, 512, 0, stream>>>(xpad, wp, out);
  } else {
    conv_gemm_fb_k<<<dim3(784, 2), 256, 0, stream>>>(x, wp, out);
  }
}